// Round 15
// baseline (93.373 us; speedup 1.0000x reference)
//
#include <hip/hip_runtime.h>
#include <hip/hip_fp16.h>

namespace {
constexpr int ICH = 8, IH = 128, IW = 128;
constexpr int CPG = 4, PH = 31;
constexpr int ICS = 516;
constexpr float EPS = 1e-5f;
constexpr float MPX = 126.f * 126.f;
constexpr int TOTAL_OUT = 128 * 64 * PH * PH;
constexpr size_t WS_NEED = (size_t)128 * 16 * 8 * 2 * 4;   // per-eighth stats

typedef _Float16 v8h __attribute__((ext_vector_type(8)));
typedef float v4f __attribute__((ext_vector_type(4)));
typedef float f32x2 __attribute__((ext_vector_type(2)));
typedef unsigned short u16;
typedef unsigned int u32;

__device__ __forceinline__ void gll16(const void* g, void* l) {
  __builtin_amdgcn_global_load_lds((const __attribute__((address_space(1))) void*)g,
                                   (__attribute__((address_space(3))) void*)l, 16, 0, 0);
}

__device__ __forceinline__ u32 pkh(float a, float b) {
  unsigned short lo = __half_as_ushort(__float2half_rn(a));
  unsigned short hi = __half_as_ushort(__float2half_rn(b));
  return (u32)lo | ((u32)hi << 16);
}

// ---------- main: implicit-GEMM conv via mfma_f32_16x16x32_f16 ----------
// Block = (n, eighth e). 4 waves x 16 oc. K = tap*8+ic (taps 0..8, pad 9..11).
// A: lane holds W[16w + (l&15)][k=(l>>4)*8+i], pre-multiplied by flip(oc);
// B: X[r+dh][c0+(l&15)+dw][ic=i].  C/D: col=l&15, row=(l>>4)*4+q [m89].
// Staging fused (T14): f32 loads -> cvt_pk f16 -> ds_write, no prepass pass.
// Stats/pool in packed f32x2 (v_pk_*), 2 accumulator sets to break fma chains.
__global__ __launch_bounds__(256, 2) void conv_mfma(
    const float* __restrict__ x, const float* __restrict__ cw,
    const float* __restrict__ cb, const float* __restrict__ gnw,
    const float* __restrict__ sc, float* __restrict__ out,
    float* __restrict__ wsp) {
  __shared__ __align__(16) u16 ring[12][1056];   // 12 rows x 132 px x 8 ic, 25344 B

  const int bid = blockIdx.x;
  const int n = bid >> 3, e = bid & 7;
  const int out_lo = e * 16;
  const int out_hi = (e == 7) ? 125 : out_lo + 15;
  const int NST = (e == 7) ? 4 : 5;              // e=7 stages rows 112..127 exactly
  const int t = threadIdx.x;
  const int w = t >> 6, l = t & 63;
  const int colB = l & 15, qt = l >> 4;

  // Zero the per-row pixel pad (px 128..131): clamped-tap lanes can read it.
  for (int idx = t; idx < 12 * 32; idx += 256)
    ring[idx >> 5][1024 + (idx & 31)] = 0;

  // A fragments (weights), zero-padded taps 9..11, flip folded in (sign of
  // gnw*sc for this A-row's oc): pool-max then needs NO per-element multiply.
  const int ocA = 16 * w + colB;
  const float flipA = (gnw[ocA] * sc[ocA] >= 0.f) ? 1.f : -1.f;
  v8h af[3];
#pragma unroll
  for (int kc = 0; kc < 3; ++kc) {
    const int tap = kc * 4 + qt;
#pragma unroll
    for (int i = 0; i < 8; ++i)
      af[kc][i] = (tap < 9) ? (_Float16)(flipA * cw[ocA * 72 + i * 9 + tap])
                            : (_Float16)0.f;
  }
  // B per-lane address constants. Pad lanes (tap>8, A==0) read offset 0:
  // same-address broadcast within the wave -> near-free LDS access.
  int eofc[3], dhl[3];
#pragma unroll
  for (int kc = 0; kc < 3; ++kc) {
    int tap = kc * 4 + qt;
    if (tap <= 8) {
      dhl[kc] = tap / 3;
      eofc[kc] = (colB + tap % 3) * 8;
    } else {
      dhl[kc] = 0;
      eofc[kc] = 0;
    }
  }
  float flip[4];
#pragma unroll
  for (int q = 0; q < 4; ++q) {
    int oc = 16 * w + qt * 4 + q;
    flip[q] = (gnw[oc] * sc[oc] >= 0.f) ? 1.f : -1.f;
  }
  const u16* rb = &ring[0][0];

  // ---- fused staging: thread t handles pixel (t&127) of rows 2*(t>>7)+{0,1} ----
  const int prg = t >> 7;                  // row-pair group 0..1
  const int px = t & 127;
  const float* xb = x + ((size_t)n * ICH) * (IH * IW) + px;
  float fs[16];                            // [rowInPair][ic], static-indexed
  auto load_regs = [&](int s) {
#pragma unroll
    for (int rr = 0; rr < 2; ++rr) {
      const int grow = out_lo + 4 * s + 2 * prg + rr;
      const float* gp = xb + (size_t)grow * IW;
#pragma unroll
      for (int ic = 0; ic < 8; ++ic)
        fs[rr * 8 + ic] = gp[(size_t)ic * (IH * IW)];
    }
  };
  auto write_lds = [&](int s) {
#pragma unroll
    for (int rr = 0; rr < 2; ++rr) {
      const int grow = out_lo + 4 * s + 2 * prg + rr;
      const int slot = grow % 12;
      uint4 v;
      v.x = pkh(fs[rr * 8 + 0], fs[rr * 8 + 1]);
      v.y = pkh(fs[rr * 8 + 2], fs[rr * 8 + 3]);
      v.z = pkh(fs[rr * 8 + 4], fs[rr * 8 + 5]);
      v.w = pkh(fs[rr * 8 + 6], fs[rr * 8 + 7]);
      *reinterpret_cast<uint4*>(&ring[slot][px * 8]) = v;
    }
  };

  load_regs(0);
  write_lds(0);

  const f32x2 ninf2 = {-3.4e38f, -3.4e38f};
  f32x2 s1a[2] = {{0.f, 0.f}, {0.f, 0.f}}, s1b[2] = {{0.f, 0.f}, {0.f, 0.f}};
  f32x2 s2a[2] = {{0.f, 0.f}, {0.f, 0.f}}, s2b[2] = {{0.f, 0.f}, {0.f, 0.f}};
  f32x2 pacc2[8][2];
#pragma unroll
  for (int ci = 0; ci < 8; ++ci) { pacc2[ci][0] = ninf2; pacc2[ci][1] = ninf2; }

  for (int s = 0; s < NST; ++s) {
    __syncthreads();                      // stage s writes visible to all waves
    if (s + 1 < NST) load_regs(s + 1);    // loads fly under the MFMA phase
#pragma unroll
    for (int ri = 0; ri < 4; ++ri) {
      const int r = out_lo + 4 * s - 2 + ri;
      if (r < out_lo || r > out_hi) continue;
      const int rm = r % 12;
      int eoff[3];
#pragma unroll
      for (int kc = 0; kc < 3; ++kc) {
        int sl = rm + dhl[kc];
        if (sl >= 12) sl -= 12;
        eoff[kc] = sl * 1056 + eofc[kc];
      }
#pragma unroll
      for (int ci = 0; ci < 8; ++ci) {
        v4f acc = {0.f, 0.f, 0.f, 0.f};   // holds flip(oc)*conv (no bias)
#pragma unroll
        for (int kc = 0; kc < 3; ++kc) {
          v8h bf = *reinterpret_cast<const v8h*>(rb + eoff[kc] + ci * 128);
          acc = __builtin_amdgcn_mfma_f32_16x16x32_f16(af[kc], bf, acc, 0, 0, 0);
        }
        f32x2 a01 = {acc[0], acc[1]};
        f32x2 a23 = {acc[2], acc[3]};
        if (ci == 7) {                     // cols 112..127: mask 126,127
          const float mv = (colB < 14) ? 1.f : 0.f;
          const f32x2 mp = {mv, mv};
          a01 *= mp; a23 *= mp;            // masked lanes contribute exact 0
          f32x2 p01 = (colB < 14) ? a01 : ninf2;
          f32x2 p23 = (colB < 14) ? a23 : ninf2;
          pacc2[7][0] = __builtin_elementwise_max(pacc2[7][0], p01);
          pacc2[7][1] = __builtin_elementwise_max(pacc2[7][1], p23);
        } else {
          pacc2[ci][0] = __builtin_elementwise_max(pacc2[ci][0], a01);
          pacc2[ci][1] = __builtin_elementwise_max(pacc2[ci][1], a23);
        }
        if (ci & 1) {
          s1b[0] += a01; s1b[1] += a23;
          s2b[0] = __builtin_elementwise_fma(a01, a01, s2b[0]);
          s2b[1] = __builtin_elementwise_fma(a23, a23, s2b[1]);
        } else {
          s1a[0] += a01; s1a[1] += a23;
          s2a[0] = __builtin_elementwise_fma(a01, a01, s2a[0]);
          s2a[1] = __builtin_elementwise_fma(a23, a23, s2a[1]);
        }
      }
      if ((r & 3) == 3) {                  // flush pool window row pr = r>>2
        const int pr = r >> 2;
        float* ob = out + (((size_t)n * 64 + 16 * w + qt * 4) * PH + pr) * PH;
#pragma unroll
        for (int ci = 0; ci < 8; ++ci) {
#pragma unroll
          for (int q = 0; q < 4; ++q) {
            float pm = pacc2[ci][q >> 1][q & 1];
            pm = fmaxf(pm, __shfl_xor(pm, 1, 64));
            pm = fmaxf(pm, __shfl_xor(pm, 2, 64));
            if ((l & 3) == 0 && (ci < 7 || colB < 12)) {  // pc<=30 only
              int pc = ci * 4 + (colB >> 2);
              ob[(size_t)q * (PH * PH) + pc] = flip[q] * pm;   // raw extreme
            }
          }
          pacc2[ci][0] = ninf2;
          pacc2[ci][1] = ninf2;
        }
      }
    }
    // ds_write stage s+1 (rows 4s+4..4s+7) -- disjoint from stage-s reads
    // (rows 4s-2..4s+3), so no barrier needed before these writes.
    if (s + 1 < NST) write_lds(s + 1);
  }

  // per-eighth stats reduce (16 lanes); un-flip s1; fold bias with eighth count.
  float s1q[4];
#pragma unroll
  for (int q = 0; q < 4; ++q) s1q[q] = s1a[q >> 1][q & 1] + s1b[q >> 1][q & 1];
  float s2g = s2a[0].x + s2a[0].y + s2a[1].x + s2a[1].y +
              s2b[0].x + s2b[0].y + s2b[1].x + s2b[1].y;
#pragma unroll
  for (int off = 1; off <= 8; off <<= 1) {
#pragma unroll
    for (int q = 0; q < 4; ++q) s1q[q] += __shfl_xor(s1q[q], off, 64);
    s2g += __shfl_xor(s2g, off, 64);
  }
  if ((l & 15) == 0) {
    const float cnte = 126.f * (float)(out_hi - out_lo + 1);   // 16 or 14 rows
    float S1 = 0.f, S2 = s2g;
#pragma unroll
    for (int q = 0; q < 4; ++q) {
      float s1t = flip[q] * s1q[q];        // undo folded flip for the mean
      float b = cb[16 * w + qt * 4 + q];
      S1 += s1t + cnte * b;
      S2 += 2.f * b * s1t + cnte * b * b;
    }
    int g = 4 * w + qt;
    float* wp = wsp + ((size_t)(n * 16 + g) * 8 + e) * 2;
    wp[0] = S1; wp[1] = S2;
  }
}

// ---------- epilogue kernel: GN affine + clamp over raw pool extremes ----------
__global__ __launch_bounds__(256) void gn_affine_clamp(
    float* __restrict__ out, const float* __restrict__ wsp,
    const float* __restrict__ gnw, const float* __restrict__ gnb,
    const float* __restrict__ sc, const float* __restrict__ cb) {
  int i = blockIdx.x * 256 + threadIdx.x;
  const int stride = gridDim.x * 256;
  for (; i < TOTAL_OUT; i += stride) {
    int c = (i / 961) & 63;
    int n = i / 61504;
    const float* wp = wsp + ((size_t)(n * 16 + (c >> 2)) * 8) * 2;
    float S1 = 0.f, S2 = 0.f;
#pragma unroll
    for (int e = 0; e < 8; ++e) { S1 += wp[2 * e]; S2 += wp[2 * e + 1]; }
    constexpr float invN = 1.f / (4.f * MPX);
    float mean = S1 * invN;
    float var = S2 * invN - mean * mean;
    float inv = rsqrtf(var + EPS);
    float gw = gnw[c];
    float A = gw * inv * sc[c];
    float B = (gnb[c] - mean * inv * gw) * sc[c] + A * cb[c];
    float v = fmaf(A, out[i], B);
    out[i] = fminf(fmaxf(v, 0.f), 1.f);
  }
}

// ---------- f32 fallback (verbatim R6 winner, used only if ws too small) ----------
#define FIN(T, DOSTATS, RE)                                                    \
  {                                                                            \
    float f0 = T[0] + __shfl_xor(T[0], 32, 64);                                \
    float f1 = T[1] + __shfl_xor(T[1], 32, 64);                                \
    float f2 = T[2] + __shfl_xor(T[2], 32, 64);                                \
    float f3 = T[3] + __shfl_xor(T[3], 32, 64);                                \
    if (DOSTATS) {                                                             \
      s1 += f0 + f1 + m23 * (f2 + f3);                                         \
      float qa = fmaf(f0, f0, f1 * f1);                                        \
      float qb = fmaf(f2, f2, f3 * f3);                                        \
      s2 += qa + m23 * qb;                                                     \
    }                                                                          \
    RE = fmaxf(fmaxf(flip * f0, flip * f1), fmaxf(flip * f2, flip * f3));      \
  }
#define ZERO(T) { T[0] = 0.f; T[1] = 0.f; T[2] = 0.f; T[3] = 0.f; }
#define ROWF(RR, T2, T1, T0)                                                   \
  {                                                                            \
    _Pragma("unroll") for (int i4 = 0; i4 < 4; ++i4) {                         \
      const float* rp = bp + (4 * p + i4) * ICS + (RR) * IW + 4 * j;           \
      float4 v4 = *reinterpret_cast<const float4*>(rp);                        \
      float2 v2 = *reinterpret_cast<const float2*>(rp + 4);                    \
      float in[6] = {v4.x, v4.y, v4.z, v4.w, v2.x, v2.y};                      \
      _Pragma("unroll") for (int dw = 0; dw < 3; ++dw) {                       \
        const float w0 = wf[i4 * 9 + dw];                                      \
        const float w1 = wf[i4 * 9 + 3 + dw];                                  \
        const float w2 = wf[i4 * 9 + 6 + dw];                                  \
        _Pragma("unroll") for (int q = 0; q < 4; ++q) {                        \
          T2[q] = fmaf(in[q + dw], w2, T2[q]);                                 \
          T1[q] = fmaf(in[q + dw], w1, T1[q]);                                 \
          T0[q] = fmaf(in[q + dw], w0, T0[q]);                                 \
        }                                                                      \
      }                                                                        \
    }                                                                          \
  }
#define STAGEF(S, X, Y, Z, DOS01, DOWIN)                                       \
  {                                                                            \
    __syncthreads();                                                           \
    const int cur = (S) & 1;                                                   \
    if ((S) < 31) issue(4 * ((S) + 1), cur ^ 1);                               \
    const float* bp = &buf[cur][0][0];                                         \
    float re0, re1, re2, re3;                                                  \
    ROWF(0, X, Y, Z) FIN(X, DOS01, re0) ZERO(X)                                \
    ROWF(1, Y, Z, X) FIN(Y, DOS01, re1) ZERO(Y)                                \
    if (DOWIN) {                                                               \
      float wfin = fmaxf(wprev, fmaxf(re0, re1));                              \
      if (p == 0 && j < 31) mm[c][(S) - 1][j] = __float2half(flip * wfin);     \
    }                                                                          \
    ROWF(2, Z, X, Y) FIN(Z, true, re2) ZERO(Z)                                 \
    ROWF(3, X, Y, Z) FIN(X, true, re3) ZERO(X)                                 \
    wprev = fmaxf(re2, re3);                                                   \
  }

__global__ __launch_bounds__(256, 2) void fused_conv_gn_pool_f32(
    const float* __restrict__ x, const float* __restrict__ cw,
    const float* __restrict__ cb, const float* __restrict__ gnw,
    const float* __restrict__ gnb, const float* __restrict__ sc,
    float* __restrict__ out) {
  __shared__ float buf[2][ICH][ICS];
  __shared__ __half mm[CPG][PH][PH];
  __shared__ float red[8];
  __shared__ float stats[2];

  const int bid = blockIdx.x;
  const int xcd = bid & 7;
  const int kb = bid >> 3;
  const int n = xcd * 16 + (kb >> 4);
  const int g = kb & 15;
  const int t = threadIdx.x;
  const int c = t >> 6;
  const int u = t & 63;
  const int p = u >> 5;
  const int j = u & 31;
  const int gc = g * CPG + c;

  float wf[36];
  {
    const float4* wp = reinterpret_cast<const float4*>(cw + gc * 72 + p * 36);
#pragma unroll
    for (int q = 0; q < 9; ++q) {
      float4 v = wp[q];
      wf[4 * q + 0] = v.x; wf[4 * q + 1] = v.y;
      wf[4 * q + 2] = v.z; wf[4 * q + 3] = v.w;
    }
  }
  const float flip = ((gnw[gc] * sc[gc]) >= 0.f) ? 1.f : -1.f;
  const float m23 = (j < 31) ? 1.f : 0.f;

  const float* xn = x + (size_t)n * ICH * IH * IW;

  auto issue = [&](int br, int which) {
#pragma unroll
    for (int k = 0; k < 4; ++k) {
      const int m = c * 4 + k;
      const int ic = m >> 1;
      const int r2 = (m & 1) * 2;
      const float* gp = xn + (size_t)(ic * IH + br + r2) * IW + u * 4;
      gll16(gp, &buf[which][ic][r2 * IW]);
    }
  };

  issue(0, 0);

  float s1 = 0.f, s2 = 0.f, wprev = 0.f;
  float A0[4] = {0, 0, 0, 0}, A1[4] = {0, 0, 0, 0}, A2[4] = {0, 0, 0, 0};

  STAGEF(0, A0, A1, A2, false, false)
  for (int s = 1; s <= 28; s += 3) {
    STAGEF(s,     A1, A2, A0, true, true)
    STAGEF(s + 1, A2, A0, A1, true, true)
    STAGEF(s + 2, A0, A1, A2, true, true)
  }
  STAGEF(31, A1, A2, A0, true, true)

#pragma unroll
  for (int off = 32; off > 0; off >>= 1) {
    s1 += __shfl_down(s1, off, 64);
    s2 += __shfl_down(s2, off, 64);
  }
  const float bc = cb[gc];
  if (u == 0) {
    float t1 = 0.5f * s1, t2 = 0.5f * s2;
    red[c * 2] = t1 + MPX * bc;
    red[c * 2 + 1] = t2 + 2.f * bc * t1 + MPX * bc * bc;
  }
  __syncthreads();
  if (t == 0) {
    float S1 = red[0] + red[2] + red[4] + red[6];
    float S2 = red[1] + red[3] + red[5] + red[7];
    constexpr float invN = 1.f / (CPG * 126.f * 126.f);
    float mean = S1 * invN;
    float var = S2 * invN - mean * mean;
    stats[0] = mean;
    stats[1] = rsqrtf(var + EPS);
  }
  __syncthreads();
  const float mean = stats[0], inv = stats[1];

  float* outp = out + ((size_t)n * 64 + g * CPG) * (PH * PH);
  for (int kk = 0; kk < 16; ++kk) {
    int idx = t + kk * 256;
    if (idx < CPG * PH * PH) {
      int cc = idx / (PH * PH);
      int rem = idx - cc * (PH * PH);
      float e = __half2float(mm[cc][rem / PH][rem % PH]);
      int gcc = g * CPG + cc;
      float gw = gnw[gcc];
      float A = gw * inv * sc[gcc];
      float B = (gnb[gcc] - mean * inv * gw) * sc[gcc] + A * cb[gcc];
      float v = fmaf(A, e, B);
      v = fminf(fmaxf(v, 0.f), 1.f);
      outp[cc * (PH * PH) + rem] = v;
    }
  }
}
}  // namespace

extern "C" void kernel_launch(void* const* d_in, const int* in_sizes, int n_in,
                              void* d_out, int out_size, void* d_ws, size_t ws_size,
                              hipStream_t stream) {
  const float* x   = (const float*)d_in[0];
  const float* cw  = (const float*)d_in[1];
  const float* cb  = (const float*)d_in[2];
  const float* gnw = (const float*)d_in[3];
  const float* gnb = (const float*)d_in[4];
  const float* sc  = (const float*)d_in[5];
  float* out = (float*)d_out;

  if (ws_size >= WS_NEED) {
    float* wsp = (float*)d_ws;
    hipLaunchKernelGGL(conv_mfma, dim3(1024), dim3(256), 0, stream,
                       x, cw, cb, gnw, sc, out, wsp);
    hipLaunchKernelGGL(gn_affine_clamp, dim3(2048), dim3(256), 0, stream,
                       out, wsp, gnw, gnb, sc, cb);
  } else {
    hipLaunchKernelGGL(fused_conv_gn_pool_f32, dim3(2048), dim3(256), 0, stream,
                       x, cw, cb, gnw, gnb, sc, out);
  }
}